// Round 2
// baseline (1398.473 us; speedup 1.0000x reference)
//
#include <hip/hip_runtime.h>
#include <hip/hip_bf16.h>

// Problem dims (from reference): N=50000 nodes, E=800000 edges, D_IN=256,
// H=256 (=2*d_out), D_OUT=128. edge_index delivered as int32 by harness.

// ---------------- degree / dinv ----------------
__global__ void degree_kernel(const int* __restrict__ dst, unsigned* __restrict__ deg, int E) {
    int e = blockIdx.x * blockDim.x + threadIdx.x;
    if (e < E) atomicAdd(&deg[dst[e]], 1u);
}

__global__ void dinv_kernel(const unsigned* __restrict__ deg, float* __restrict__ dinv, int N) {
    int i = blockIdx.x * blockDim.x + threadIdx.x;
    if (i < N) dinv[i] = rsqrtf((float)(deg[i] + 1u));  // +1 for the self-loop
}

// ---------------- fp32 tiled GEMM: C[MxN] = A[MxK] @ B[KxN] ----------------
// 64x64 block tile, BK=16, 256 threads, 4x4 micro-tile per thread.
#define BM 64
#define BN 64
#define BK 16
__global__ __launch_bounds__(256) void gemm_f32(const float* __restrict__ A,
                                                const float* __restrict__ B,
                                                float* __restrict__ C,
                                                int M, int N, int K) {
    __shared__ float As[BK][BM + 1];
    __shared__ float Bs[BK][BN + 1];
    const int tid = threadIdx.x;           // 0..255
    const int tx = tid % 16;               // micro-tile col group
    const int ty = tid / 16;               // micro-tile row group
    const int row0 = blockIdx.y * BM;
    const int col0 = blockIdx.x * BN;

    float acc[4][4] = {};

    for (int k0 = 0; k0 < K; k0 += BK) {
        // A tile: BM x BK (1024 elems, 4 per thread)
#pragma unroll
        for (int i = 0; i < 4; i++) {
            int idx = tid + i * 256;
            int m = idx / BK;
            int kk = idx % BK;
            int gm = row0 + m;
            As[kk][m] = (gm < M) ? A[(long)gm * K + k0 + kk] : 0.f;
        }
        // B tile: BK x BN (N multiple of BN, K multiple of BK -> no guard)
#pragma unroll
        for (int i = 0; i < 4; i++) {
            int idx = tid + i * 256;
            int kk = idx / BN;
            int nn = idx % BN;
            Bs[kk][nn] = B[(long)(k0 + kk) * N + col0 + nn];
        }
        __syncthreads();
#pragma unroll
        for (int kk = 0; kk < BK; kk++) {
            float a[4], b[4];
#pragma unroll
            for (int i = 0; i < 4; i++) a[i] = As[kk][ty * 4 + i];
#pragma unroll
            for (int j = 0; j < 4; j++) b[j] = Bs[kk][tx * 4 + j];
#pragma unroll
            for (int i = 0; i < 4; i++)
#pragma unroll
                for (int j = 0; j < 4; j++) acc[i][j] += a[i] * b[j];
        }
        __syncthreads();
    }

#pragma unroll
    for (int i = 0; i < 4; i++) {
        int gm = row0 + ty * 4 + i;
        if (gm < M) {
#pragma unroll
            for (int j = 0; j < 4; j++) {
                C[(long)gm * N + col0 + tx * 4 + j] = acc[i][j];
            }
        }
    }
}

// ---------------- edge scatter (push, atomics) ----------------
// One wave (64 lanes) per edge; lanes stride over F features.
__global__ __launch_bounds__(256) void scatter_kernel(const float* __restrict__ h,
                                                      const int* __restrict__ src,
                                                      const int* __restrict__ dst,
                                                      const float* __restrict__ dinv,
                                                      float* __restrict__ agg,
                                                      int E, int F) {
    int wave = (blockIdx.x * blockDim.x + threadIdx.x) >> 6;
    int lane = threadIdx.x & 63;
    if (wave >= E) return;
    int s = src[wave];
    int d = dst[wave];
    float w = dinv[s] * dinv[d];
    const float* hrow = h + (long)s * F;
    float* arow = agg + (long)d * F;
    for (int i = lane; i < F; i += 64) {
        atomicAdd(&arow[i], hrow[i] * w);
    }
}

// ---------------- self-loop + bias + relu ----------------
__global__ __launch_bounds__(256) void finish_kernel(const float* __restrict__ agg,
                                                     const float* __restrict__ h,
                                                     const float* __restrict__ dinv,
                                                     const float* __restrict__ bias,
                                                     float* __restrict__ out,
                                                     int N, int F) {
    long idx = (long)blockIdx.x * blockDim.x + threadIdx.x;
    if (idx >= (long)N * F) return;
    int i = (int)(idx / F);
    int j = (int)(idx % F);
    float di = dinv[i];
    float v = agg[idx] + h[idx] * di * di + bias[j];
    out[idx] = v > 0.f ? v : 0.f;
}

extern "C" void kernel_launch(void* const* d_in, const int* in_sizes, int n_in,
                              void* d_out, int out_size, void* d_ws, size_t ws_size,
                              hipStream_t stream) {
    const float* x  = (const float*)d_in[0];   // [N, 256]
    const int* ei   = (const int*)d_in[1];     // [2, E] (harness converts int64 -> int32)
    const float* W1 = (const float*)d_in[2];   // [256, 256]
    const float* b1 = (const float*)d_in[3];   // [256]
    const float* W2 = (const float*)d_in[4];   // [256, 128]
    const float* b2 = (const float*)d_in[5];   // [128]

    const int DIN = 256;
    const int N = in_sizes[0] / DIN;        // 50000
    const int E = in_sizes[1] / 2;          // 800000
    const int H = in_sizes[3];              // 256
    const int DOUT = in_sizes[5];           // 128

    const int* src = ei;
    const int* dst = ei + E;

    // workspace layout (h2 aliases h1 — h1 is dead after finish_kernel of layer 1)
    char* ws = (char*)d_ws;
    unsigned* deg = (unsigned*)ws;                 ws += (size_t)N * 4;
    float* dinv   = (float*)ws;                    ws += (size_t)N * 4;
    float* h1     = (float*)ws;                    ws += (size_t)N * H * 4;
    float* agg1   = (float*)ws;                    ws += (size_t)N * H * 4;   // relu(layer1) in-place
    float* h2     = h1;                            // alias: N*DOUT*4 <= N*H*4
    float* outp   = (float*)d_out;                 // agg2 accumulates here

    // zero accumulators (d_out / d_ws are poisoned with 0xAA)
    hipMemsetAsync(deg, 0, (size_t)N * 4, stream);
    hipMemsetAsync(agg1, 0, (size_t)N * H * 4, stream);
    hipMemsetAsync(outp, 0, (size_t)N * DOUT * 4, stream);

    // degree + dinv
    degree_kernel<<<(E + 255) / 256, 256, 0, stream>>>(dst, deg, E);
    dinv_kernel<<<(N + 255) / 256, 256, 0, stream>>>(deg, dinv, N);

    // layer 1: h1 = x @ W1
    {
        dim3 grid(H / BN, (N + BM - 1) / BM);
        gemm_f32<<<grid, 256, 0, stream>>>(x, W1, h1, N, H, DIN);
    }
    // scatter edges into agg1
    {
        long threads = (long)E * 64;
        scatter_kernel<<<(int)((threads + 255) / 256), 256, 0, stream>>>(h1, src, dst, dinv, agg1, E, H);
    }
    // self-loop + bias + relu (in-place into agg1)
    finish_kernel<<<(int)(((long)N * H + 255) / 256), 256, 0, stream>>>(agg1, h1, dinv, b1, agg1, N, H);

    // layer 2: h2 = y1 @ W2   (h2 aliases h1's storage)
    {
        dim3 grid(DOUT / BN, (N + BM - 1) / BM);
        gemm_f32<<<grid, 256, 0, stream>>>(agg1, W2, h2, N, DOUT, H);
    }
    // scatter edges into d_out
    {
        long threads = (long)E * 64;
        scatter_kernel<<<(int)((threads + 255) / 256), 256, 0, stream>>>(h2, src, dst, dinv, outp, E, DOUT);
    }
    // self-loop + bias + relu (in-place into d_out)
    finish_kernel<<<(int)(((long)N * DOUT + 255) / 256), 256, 0, stream>>>(outp, h2, dinv, b2, outp, N, DOUT);
}

// Round 3
// 689.684 us; speedup vs baseline: 2.0277x; 2.0277x over previous
//
#include <hip/hip_runtime.h>
#include <hip/hip_bf16.h>

// GCN 2-layer: N=50000, E=800000, D_IN=256, H=256, D_OUT=128.
// Round 3: CSR pull-gather (no float atomics), fused self-loop+bias+relu.

// ---------------- degree / dinv ----------------
__global__ void degree_kernel(const int* __restrict__ dst, unsigned* __restrict__ deg, int E) {
    int e = blockIdx.x * blockDim.x + threadIdx.x;
    if (e < E) atomicAdd(&deg[dst[e]], 1u);
}

__global__ void dinv_kernel(const unsigned* __restrict__ deg, float* __restrict__ dinv, int N) {
    int i = blockIdx.x * blockDim.x + threadIdx.x;
    if (i < N) dinv[i] = rsqrtf((float)(deg[i] + 1u));  // +1 for the self-loop
}

// ---------------- exclusive scan over deg -> rowptr & cursor ----------------
// Single block, 1024 threads, Hillis-Steele per 1024-chunk with running carry.
// N=50K -> ~49 chunks; trivial cost.
__global__ __launch_bounds__(1024) void scan_kernel(const unsigned* __restrict__ deg,
                                                    int* __restrict__ rowptr,
                                                    int* __restrict__ cursor, int N) {
    __shared__ int tmp[1024];
    __shared__ int carry_s;
    const int t = threadIdx.x;
    if (t == 0) carry_s = 0;
    __syncthreads();
    for (int base = 0; base < N; base += 1024) {
        int i = base + t;
        int v = (i < N) ? (int)deg[i] : 0;
        tmp[t] = v;
        __syncthreads();
        for (int off = 1; off < 1024; off <<= 1) {
            int add = (t >= off) ? tmp[t - off] : 0;
            __syncthreads();
            tmp[t] += add;
            __syncthreads();
        }
        int incl = tmp[t];
        int excl = incl - v;
        int c = carry_s;
        if (i < N) {
            rowptr[i] = c + excl;
            cursor[i] = c + excl;
        }
        __syncthreads();
        if (t == 1023) carry_s = c + incl;
        __syncthreads();
    }
    if (t == 0) rowptr[N] = carry_s;
}

// ---------------- CSR fill (int atomics on 50K cursors) ----------------
__global__ __launch_bounds__(256) void fill_kernel(const int* __restrict__ src,
                                                   const int* __restrict__ dst,
                                                   const float* __restrict__ dinv,
                                                   int* __restrict__ cursor,
                                                   int* __restrict__ col,
                                                   float* __restrict__ wgt, int E) {
    int e = blockIdx.x * blockDim.x + threadIdx.x;
    if (e < E) {
        int d = dst[e];
        int s = src[e];
        int pos = atomicAdd(&cursor[d], 1);
        col[pos] = s;
        wgt[pos] = dinv[s] * dinv[d];
    }
}

// ---------------- fp32 tiled GEMM: C[MxN] = A[MxK] @ B[KxN] ----------------
#define BM 64
#define BN 64
#define BK 16
__global__ __launch_bounds__(256) void gemm_f32(const float* __restrict__ A,
                                                const float* __restrict__ B,
                                                float* __restrict__ C,
                                                int M, int N, int K) {
    __shared__ float As[BK][BM + 1];
    __shared__ float Bs[BK][BN + 1];
    const int tid = threadIdx.x;
    const int tx = tid % 16;
    const int ty = tid / 16;
    const int row0 = blockIdx.y * BM;
    const int col0 = blockIdx.x * BN;

    float acc[4][4] = {};

    for (int k0 = 0; k0 < K; k0 += BK) {
#pragma unroll
        for (int i = 0; i < 4; i++) {
            int idx = tid + i * 256;
            int m = idx / BK;
            int kk = idx % BK;
            int gm = row0 + m;
            As[kk][m] = (gm < M) ? A[(long)gm * K + k0 + kk] : 0.f;
        }
#pragma unroll
        for (int i = 0; i < 4; i++) {
            int idx = tid + i * 256;
            int kk = idx / BN;
            int nn = idx % BN;
            Bs[kk][nn] = B[(long)(k0 + kk) * N + col0 + nn];
        }
        __syncthreads();
#pragma unroll
        for (int kk = 0; kk < BK; kk++) {
            float a[4], b[4];
#pragma unroll
            for (int i = 0; i < 4; i++) a[i] = As[kk][ty * 4 + i];
#pragma unroll
            for (int j = 0; j < 4; j++) b[j] = Bs[kk][tx * 4 + j];
#pragma unroll
            for (int i = 0; i < 4; i++)
#pragma unroll
                for (int j = 0; j < 4; j++) acc[i][j] += a[i] * b[j];
        }
        __syncthreads();
    }

#pragma unroll
    for (int i = 0; i < 4; i++) {
        int gm = row0 + ty * 4 + i;
        if (gm < M) {
#pragma unroll
            for (int j = 0; j < 4; j++) {
                C[(long)gm * N + col0 + tx * 4 + j] = acc[i][j];
            }
        }
    }
}

// ---------------- CSR pull-gather + self-loop + bias + relu (fused) -------
// One block per node, one thread per feature (F = blockDim.x, 128 or 256).
// Row edges iterated sequentially, 4-way unrolled for gather ILP.
__global__ void gather_kernel(const float* __restrict__ h,
                              const int* __restrict__ rowptr,
                              const int* __restrict__ col,
                              const float* __restrict__ wgt,
                              const float* __restrict__ dinv,
                              const float* __restrict__ bias,
                              float* __restrict__ out,
                              int F) {
    const int node = blockIdx.x;
    const int t = threadIdx.x;              // 0..F-1
    const int beg = rowptr[node];
    const int end = rowptr[node + 1];

    float acc = 0.f;
    int e = beg;
    for (; e + 4 <= end; e += 4) {
        int s0 = col[e], s1 = col[e + 1], s2 = col[e + 2], s3 = col[e + 3];
        float w0 = wgt[e], w1 = wgt[e + 1], w2 = wgt[e + 2], w3 = wgt[e + 3];
        float v0 = h[(long)s0 * F + t];
        float v1 = h[(long)s1 * F + t];
        float v2 = h[(long)s2 * F + t];
        float v3 = h[(long)s3 * F + t];
        acc += v0 * w0 + v1 * w1 + v2 * w2 + v3 * w3;
    }
    for (; e < end; e++) {
        acc += h[(long)col[e] * F + t] * wgt[e];
    }
    float di = dinv[node];
    float v = acc + h[(long)node * F + t] * di * di + bias[t];
    out[(long)node * F + t] = fmaxf(v, 0.f);
}

extern "C" void kernel_launch(void* const* d_in, const int* in_sizes, int n_in,
                              void* d_out, int out_size, void* d_ws, size_t ws_size,
                              hipStream_t stream) {
    const float* x  = (const float*)d_in[0];   // [N, 256]
    const int* ei   = (const int*)d_in[1];     // [2, E] (harness delivers int32)
    const float* W1 = (const float*)d_in[2];   // [256, 256]
    const float* b1 = (const float*)d_in[3];   // [256]
    const float* W2 = (const float*)d_in[4];   // [256, 128]
    const float* b2 = (const float*)d_in[5];   // [128]

    const int DIN = 256;
    const int N = in_sizes[0] / DIN;        // 50000
    const int E = in_sizes[1] / 2;          // 800000
    const int H = in_sizes[3];              // 256
    const int DOUT = in_sizes[5];           // 128

    const int* src = ei;
    const int* dst = ei + E;

    // workspace layout
    char* ws = (char*)d_ws;
    unsigned* deg = (unsigned*)ws;                 ws += (size_t)N * 4;
    float* dinv   = (float*)ws;                    ws += (size_t)N * 4;
    int* rowptr   = (int*)ws;                      ws += (size_t)(N + 1) * 4;
    int* cursor   = (int*)ws;                      ws += (size_t)N * 4;
    int* col      = (int*)ws;                      ws += (size_t)E * 4;
    float* wgt    = (float*)ws;                    ws += (size_t)E * 4;
    float* h1     = (float*)ws;                    ws += (size_t)N * H * 4;
    float* y1     = (float*)ws;                    ws += (size_t)N * H * 4;
    float* h2     = h1;                            // h1 dead after gather1
    float* outp   = (float*)d_out;

    // ---- CSR build ----
    hipMemsetAsync(deg, 0, (size_t)N * 4, stream);
    degree_kernel<<<(E + 255) / 256, 256, 0, stream>>>(dst, deg, E);
    dinv_kernel<<<(N + 255) / 256, 256, 0, stream>>>(deg, dinv, N);
    scan_kernel<<<1, 1024, 0, stream>>>(deg, rowptr, cursor, N);
    fill_kernel<<<(E + 255) / 256, 256, 0, stream>>>(src, dst, dinv, cursor, col, wgt, E);

    // ---- layer 1 ----
    {
        dim3 grid(H / BN, (N + BM - 1) / BM);
        gemm_f32<<<grid, 256, 0, stream>>>(x, W1, h1, N, H, DIN);
    }
    gather_kernel<<<N, H, 0, stream>>>(h1, rowptr, col, wgt, dinv, b1, y1, H);

    // ---- layer 2 ----
    {
        dim3 grid(DOUT / BN, (N + BM - 1) / BM);
        gemm_f32<<<grid, 256, 0, stream>>>(y1, W2, h2, N, DOUT, H);
    }
    gather_kernel<<<N, DOUT, 0, stream>>>(h2, rowptr, col, wgt, dinv, b2, outp, DOUT);
}

// Round 4
// 380.306 us; speedup vs baseline: 3.6772x; 1.8135x over previous
//
#include <hip/hip_runtime.h>
#include <hip/hip_bf16.h>

// 2-layer GCN, N=50000, E=800000, D_IN=256, H=256, D_OUT=128.
// Round 4: bf16 MFMA GEMMs (m97-style global_load_lds staging, XOR-swizzled
// LDS), bf16 intermediates to halve gather traffic, shuffle-based scan.

typedef __attribute__((ext_vector_type(8))) short bf16x8;
typedef __attribute__((ext_vector_type(4))) float f32x4;

__device__ inline float bf2f(unsigned short u) {
    return __uint_as_float(((unsigned)u) << 16);
}
__device__ inline unsigned short f2bf(float f) {
    unsigned x = __float_as_uint(f);
    unsigned r = (x + 0x7fffu + ((x >> 16) & 1u)) >> 16;   // RNE
    return (unsigned short)r;
}

// ---------------- degree / dinv ----------------
__global__ void degree_kernel(const int* __restrict__ dst, unsigned* __restrict__ deg, int E) {
    int e = blockIdx.x * blockDim.x + threadIdx.x;
    if (e < E) atomicAdd(&deg[dst[e]], 1u);
}

__global__ void dinv_kernel(const unsigned* __restrict__ deg, float* __restrict__ dinv, int N) {
    int i = blockIdx.x * blockDim.x + threadIdx.x;
    if (i < N) dinv[i] = rsqrtf((float)(deg[i] + 1u));  // +1 self-loop
}

// ---------------- exclusive scan (shuffle wave-scans, 3 barriers/chunk) ----
__global__ __launch_bounds__(1024) void scan_kernel(const unsigned* __restrict__ deg,
                                                    int* __restrict__ rowptr,
                                                    int* __restrict__ cursor, int N) {
    __shared__ int wsum[16];
    __shared__ int carry_s;
    const int t = threadIdx.x, lane = t & 63, w = t >> 6;
    if (t == 0) carry_s = 0;
    __syncthreads();
    for (int base = 0; base < N; base += 1024) {
        int i = base + t;
        int v = (i < N) ? (int)deg[i] : 0;
        int x = v;
#pragma unroll
        for (int off = 1; off < 64; off <<= 1) {
            int y = __shfl_up(x, off, 64);
            if (lane >= off) x += y;
        }
        if (lane == 63) wsum[w] = x;
        __syncthreads();
        if (w == 0 && lane < 16) {
            int s = wsum[lane];
#pragma unroll
            for (int off = 1; off < 16; off <<= 1) {
                int y = __shfl_up(s, off, 16);
                if ((lane & 15) >= off) s += y;
            }
            wsum[lane] = s;   // inclusive over wave sums
        }
        __syncthreads();
        int waveoff = (w == 0) ? 0 : wsum[w - 1];
        int incl = x + waveoff;
        int excl = incl - v;
        int c = carry_s;
        if (i < N) { rowptr[i] = c + excl; cursor[i] = c + excl; }
        __syncthreads();
        if (t == 1023) carry_s = c + incl;
        __syncthreads();
    }
    if (t == 0) rowptr[N] = carry_s;
}

// ---------------- CSR fill ----------------
__global__ __launch_bounds__(256) void fill_kernel(const int* __restrict__ src,
                                                   const int* __restrict__ dst,
                                                   const float* __restrict__ dinv,
                                                   int* __restrict__ cursor,
                                                   int* __restrict__ col,
                                                   float* __restrict__ wgt, int E) {
    int e = blockIdx.x * blockDim.x + threadIdx.x;
    if (e < E) {
        int d = dst[e];
        int s = src[e];
        int pos = atomicAdd(&cursor[d], 1);
        col[pos] = s;
        wgt[pos] = dinv[s] * dinv[d];
    }
}

// ---------------- fp32 -> bf16 convert (x) ----------------
__global__ __launch_bounds__(256) void convert_x_kernel(const float* __restrict__ in,
                                                        unsigned short* __restrict__ out,
                                                        long n4) {
    long i = (long)blockIdx.x * blockDim.x + threadIdx.x;
    if (i < n4) {
        float4 v = ((const float4*)in)[i];
        ushort4 o;
        o.x = f2bf(v.x); o.y = f2bf(v.y); o.z = f2bf(v.z); o.w = f2bf(v.w);
        ((ushort4*)out)[i] = o;
    }
}

// ---------------- fp32 W[K][Nw] -> bf16 WT[Nw][K] ----------------
__global__ __launch_bounds__(256) void convert_wt_kernel(const float* __restrict__ W,
                                                         unsigned short* __restrict__ WT,
                                                         int K, int Nw) {
    int id = blockIdx.x * blockDim.x + threadIdx.x;
    if (id < K * Nw) {
        int k = id / Nw;
        int n = id % Nw;
        WT[(long)n * K + k] = f2bf(W[id]);
    }
}

// ---------------- bf16 MFMA GEMM: C[M][Nc] = A[M,K] * BT[Nc,K]^T ----------
// 128x128 tile, BK=64, 256 threads (4 waves, each 64x64), global_load_lds
// width-16 staging, 16B-chunk XOR swizzle (2-way bank aliasing = free).
#define GBM 128
#define GBN 128
#define GBK 64
__global__ __launch_bounds__(256) void gemm_bf16(const unsigned short* __restrict__ A,
                                                 const unsigned short* __restrict__ BT,
                                                 unsigned short* __restrict__ C,
                                                 int M, int Nc, int K) {
    __shared__ __align__(16) unsigned short As[GBM * GBK];
    __shared__ __align__(16) unsigned short Bs[GBN * GBK];
    const int t = threadIdx.x;
    const int lane = t & 63;
    const int w = t >> 6;
    const int row0 = blockIdx.x * GBM;
    const int col0 = blockIdx.y * GBN;
    const int rb = (w >> 1) * 64;    // wave row base in tile
    const int cb = (w & 1) * 64;     // wave col base in tile

    f32x4 acc[4][4] = {};

    for (int kb = 0; kb < K; kb += GBK) {
        // ---- stage A tile (128 rows x 64 k) : 1024 16B chunks ----
#pragma unroll
        for (int i = 0; i < 4; i++) {
            int p = i * 256 + t;
            int row = p >> 3;
            int slot = p & 7;
            int chunk = slot ^ (row & 7);
            int grow = row0 + row;
            if (grow >= M) grow = M - 1;          // clamp; garbage rows never stored
            const unsigned short* src = A + (size_t)grow * K + kb + chunk * 8;
            __builtin_amdgcn_global_load_lds(
                (const __attribute__((address_space(1))) void*)src,
                (__attribute__((address_space(3))) void*)&As[p * 8], 16, 0, 0);
        }
        // ---- stage B tile (128 n-rows x 64 k) ----
#pragma unroll
        for (int i = 0; i < 4; i++) {
            int p = i * 256 + t;
            int row = p >> 3;
            int slot = p & 7;
            int chunk = slot ^ (row & 7);
            const unsigned short* src = BT + (size_t)(col0 + row) * K + kb + chunk * 8;
            __builtin_amdgcn_global_load_lds(
                (const __attribute__((address_space(1))) void*)src,
                (__attribute__((address_space(3))) void*)&Bs[p * 8], 16, 0, 0);
        }
        asm volatile("s_waitcnt vmcnt(0)" ::: "memory");
        __syncthreads();

        // ---- compute: 2 k-steps of 32, 16 MFMAs each per wave ----
#pragma unroll
        for (int ks = 0; ks < 2; ks++) {
            int kq = ks * 4 + (lane >> 4);      // global 8-elem chunk index 0..7
            int rsel = lane & 15;
            bf16x8 af[4], bfr[4];
#pragma unroll
            for (int mt = 0; mt < 4; mt++) {
                int m = rb + mt * 16 + rsel;
                int slot = kq ^ (m & 7);
                af[mt] = *(const bf16x8*)&As[m * GBK + slot * 8];
            }
#pragma unroll
            for (int nt = 0; nt < 4; nt++) {
                int n = cb + nt * 16 + rsel;
                int slot = kq ^ (n & 7);
                bfr[nt] = *(const bf16x8*)&Bs[n * GBK + slot * 8];
            }
#pragma unroll
            for (int mt = 0; mt < 4; mt++)
#pragma unroll
                for (int nt = 0; nt < 4; nt++)
                    acc[mt][nt] = __builtin_amdgcn_mfma_f32_16x16x32_bf16(
                        af[mt], bfr[nt], acc[mt][nt], 0, 0, 0);
        }
        __syncthreads();
    }

    // ---- epilogue: C layout col=lane&15, row=4*(lane>>4)+r (m89-verified) --
#pragma unroll
    for (int mt = 0; mt < 4; mt++) {
#pragma unroll
        for (int nt = 0; nt < 4; nt++) {
            int gcol = col0 + cb + nt * 16 + (lane & 15);
            int grow0 = row0 + rb + mt * 16 + 4 * (lane >> 4);
#pragma unroll
            for (int r = 0; r < 4; r++) {
                int g = grow0 + r;
                if (g < M) C[(size_t)g * Nc + gcol] = f2bf(acc[mt][nt][r]);
            }
        }
    }
}

// ---------------- CSR pull-gather (bf16 h) + self-loop + bias + relu ------
// One block per node; each thread owns 2 consecutive features (ushort2 loads).
template <bool OUT_BF16>
__global__ void gather_kernel(const unsigned short* __restrict__ h,
                              const int* __restrict__ rowptr,
                              const int* __restrict__ col,
                              const float* __restrict__ wgt,
                              const float* __restrict__ dinv,
                              const float* __restrict__ bias,
                              void* __restrict__ out,
                              int F) {
    const int node = blockIdx.x;
    const int f0 = 2 * threadIdx.x;
    const int beg = rowptr[node];
    const int end = rowptr[node + 1];

    float a0 = 0.f, a1 = 0.f;
    int e = beg;
    for (; e + 4 <= end; e += 4) {
        int s0 = col[e], s1 = col[e + 1], s2 = col[e + 2], s3 = col[e + 3];
        float w0 = wgt[e], w1 = wgt[e + 1], w2 = wgt[e + 2], w3 = wgt[e + 3];
        ushort2 u0 = *(const ushort2*)&h[(size_t)s0 * F + f0];
        ushort2 u1 = *(const ushort2*)&h[(size_t)s1 * F + f0];
        ushort2 u2 = *(const ushort2*)&h[(size_t)s2 * F + f0];
        ushort2 u3 = *(const ushort2*)&h[(size_t)s3 * F + f0];
        a0 += bf2f(u0.x) * w0 + bf2f(u1.x) * w1 + bf2f(u2.x) * w2 + bf2f(u3.x) * w3;
        a1 += bf2f(u0.y) * w0 + bf2f(u1.y) * w1 + bf2f(u2.y) * w2 + bf2f(u3.y) * w3;
    }
    for (; e < end; e++) {
        int s = col[e];
        float wv = wgt[e];
        ushort2 u = *(const ushort2*)&h[(size_t)s * F + f0];
        a0 += bf2f(u.x) * wv;
        a1 += bf2f(u.y) * wv;
    }
    float di = dinv[node];
    ushort2 us = *(const ushort2*)&h[(size_t)node * F + f0];
    float2 bv = *(const float2*)&bias[f0];
    float v0 = fmaxf(a0 + bf2f(us.x) * di * di + bv.x, 0.f);
    float v1 = fmaxf(a1 + bf2f(us.y) * di * di + bv.y, 0.f);
    if (OUT_BF16) {
        ushort2 o; o.x = f2bf(v0); o.y = f2bf(v1);
        *(ushort2*)&((unsigned short*)out)[(size_t)node * F + f0] = o;
    } else {
        float2 o; o.x = v0; o.y = v1;
        *(float2*)&((float*)out)[(size_t)node * F + f0] = o;
    }
}

extern "C" void kernel_launch(void* const* d_in, const int* in_sizes, int n_in,
                              void* d_out, int out_size, void* d_ws, size_t ws_size,
                              hipStream_t stream) {
    const float* x  = (const float*)d_in[0];   // [N, 256]
    const int* ei   = (const int*)d_in[1];     // [2, E] int32
    const float* W1 = (const float*)d_in[2];   // [256, 256]
    const float* b1 = (const float*)d_in[3];   // [256]
    const float* W2 = (const float*)d_in[4];   // [256, 128]
    const float* b2 = (const float*)d_in[5];   // [128]

    const int DIN = 256;
    const int N = in_sizes[0] / DIN;        // 50000
    const int E = in_sizes[1] / 2;          // 800000
    const int H = in_sizes[3];              // 256
    const int DOUT = in_sizes[5];           // 128

    const int* src = ei;
    const int* dst = ei + E;

    // workspace layout
    char* ws = (char*)d_ws;
    unsigned* deg = (unsigned*)ws;                   ws += (size_t)N * 4;
    float* dinv   = (float*)ws;                      ws += (size_t)N * 4;
    int* rowptr   = (int*)ws;                        ws += (size_t)(N + 4) * 4;
    int* cursor   = (int*)ws;                        ws += (size_t)N * 4;
    int* col      = (int*)ws;                        ws += (size_t)E * 4;
    float* wgt    = (float*)ws;                      ws += (size_t)E * 4;
    unsigned short* xb  = (unsigned short*)ws;       ws += (size_t)N * DIN * 2;
    unsigned short* w1t = (unsigned short*)ws;       ws += (size_t)DIN * H * 2;
    unsigned short* w2t = (unsigned short*)ws;       ws += (size_t)H * DOUT * 2;
    unsigned short* h1b = (unsigned short*)ws;       ws += (size_t)N * H * 2;
    unsigned short* y1b = (unsigned short*)ws;       ws += (size_t)N * H * 2;
    unsigned short* h2b = xb;                        // xb dead after gemm1
    float* outp = (float*)d_out;

    // ---- CSR build ----
    hipMemsetAsync(deg, 0, (size_t)N * 4, stream);
    degree_kernel<<<(E + 255) / 256, 256, 0, stream>>>(dst, deg, E);
    dinv_kernel<<<(N + 255) / 256, 256, 0, stream>>>(deg, dinv, N);
    scan_kernel<<<1, 1024, 0, stream>>>(deg, rowptr, cursor, N);
    fill_kernel<<<(E + 255) / 256, 256, 0, stream>>>(src, dst, dinv, cursor, col, wgt, E);

    // ---- conversions ----
    {
        long n4 = (long)N * DIN / 4;
        convert_x_kernel<<<(int)((n4 + 255) / 256), 256, 0, stream>>>(x, xb, n4);
        convert_wt_kernel<<<(DIN * H + 255) / 256, 256, 0, stream>>>(W1, w1t, DIN, H);
        convert_wt_kernel<<<(H * DOUT + 255) / 256, 256, 0, stream>>>(W2, w2t, H, DOUT);
    }

    // ---- layer 1: h1 = x @ W1 (bf16 MFMA) ----
    {
        dim3 grid((N + GBM - 1) / GBM, H / GBN);
        gemm_bf16<<<grid, 256, 0, stream>>>(xb, w1t, h1b, N, H, DIN);
    }
    gather_kernel<true><<<N, H / 2, 0, stream>>>(h1b, rowptr, col, wgt, dinv, b1, y1b, H);

    // ---- layer 2: h2 = y1 @ W2 (bf16 MFMA) ----
    {
        dim3 grid((N + GBM - 1) / GBM, DOUT / GBN);
        gemm_bf16<<<grid, 256, 0, stream>>>(y1b, w2t, h2b, N, DOUT, H);
    }
    gather_kernel<false><<<N, DOUT / 2, 0, stream>>>(h2b, rowptr, col, wgt, dinv, b2, outp, DOUT);
}